// Round 2
// baseline (9101.773 us; speedup 1.0000x reference)
//
#include <hip/hip_runtime.h>
#include <cstdint>
#include <cstddef>

#define B_    256
#define T_    128
#define SIG_  64
#define MET_  32
#define H_    256
#define F_    16
#define NCOL  1040   // [i:0..255 | ste:256..511 | c:512..767 | o:768..1023 | fre:1024..1039]

__device__ __forceinline__ float hsig(float x) {
    return fminf(fmaxf(x * (1.0f/6.0f) + 0.5f, 0.0f), 1.0f);
}

__device__ __forceinline__ unsigned short f2bf(float f) {
    unsigned int u = __float_as_uint(f);
    unsigned int r = (u + 0x7fffu + ((u >> 16) & 1u)) >> 16;
    return (unsigned short)r;
}

// column order: i(256) | ste(256) | c(256) | o(256) | fre(16)
__device__ __forceinline__ void colmap(int n, int& sec, int& idx) {
    if (n < 256)       { sec = 0; idx = n; }
    else if (n < 512)  { sec = 1; idx = n - 256; }
    else if (n < 768)  { sec = 2; idx = n - 512; }
    else if (n < 1024) { sec = 3; idx = n - 768; }
    else               { sec = 4; idx = n - 1024; }
}

// ---------------------------------------------------------------------------
// Pack weights: Wcat[96][1040] f32, bcat[1040] f32, UT[1040][256] bf16 (U^T)
// ---------------------------------------------------------------------------
__global__ __launch_bounds__(256) void pack_kernel(
    const float* __restrict__ Wis, const float* __restrict__ Wstes, const float* __restrict__ Wfres,
    const float* __restrict__ Wcs, const float* __restrict__ Wos,
    const float* __restrict__ Wim, const float* __restrict__ Wstem, const float* __restrict__ Wfrem,
    const float* __restrict__ Wcm, const float* __restrict__ Wom,
    const float* __restrict__ Ui, const float* __restrict__ Uste, const float* __restrict__ Ufre,
    const float* __restrict__ Uc, const float* __restrict__ Uo,
    const float* __restrict__ bi, const float* __restrict__ bste, const float* __restrict__ bfre,
    const float* __restrict__ bc, const float* __restrict__ bo,
    float* __restrict__ Wcat, float* __restrict__ bcat, unsigned short* __restrict__ UT)
{
    int gtid = blockIdx.x * blockDim.x + threadIdx.x;
    int stride = gridDim.x * blockDim.x;
    const float* Wsig[5] = {Wis, Wstes, Wcs, Wos, Wfres};
    const float* Wmet[5] = {Wim, Wstem, Wcm, Wom, Wfrem};
    const float* Us[5]   = {Ui, Uste, Uc, Uo, Ufre};
    const float* bs[5]   = {bi, bste, bc, bo, bfre};

    for (int i = gtid; i < 96*NCOL; i += stride) {
        int k = i / NCOL, n = i - k*NCOL;
        int sec, idx; colmap(n, sec, idx);
        int secN = (sec == 4) ? F_ : H_;
        float v = (k < 64) ? Wsig[sec][k*secN + idx] : Wmet[sec][(k-64)*secN + idx];
        Wcat[k*NCOL + n] = v;
    }
    for (int n = gtid; n < NCOL; n += stride) {
        int sec, idx; colmap(n, sec, idx);
        bcat[n] = bs[sec][idx];
    }
    for (int i = gtid; i < NCOL*H_; i += stride) {
        int n = i >> 8, k = i & 255;
        int sec, idx; colmap(n, sec, idx);
        int secN = (sec == 4) ? F_ : H_;
        UT[n*H_ + k] = f2bf(Us[sec][k*secN + idx]);
    }
}

// ---------------------------------------------------------------------------
// Phase 1: input projection GEMM for ALL time steps (z = chunk of 16 steps).
// X[(b*T + t)][n] = sum_k A * Wcat + bcat
// ---------------------------------------------------------------------------
__global__ __launch_bounds__(256) void proj_kernel(
    const float* __restrict__ sig, const float* __restrict__ met,
    const float* __restrict__ Wcat, const float* __restrict__ bcat,
    float* __restrict__ X)
{
    __shared__ float A_s[32][128];
    __shared__ float W_s[32][128];
    int tid = threadIdx.x;
    int c0b = blockIdx.x * 128;
    int m0  = blockIdx.y * 128;
    int t0  = blockIdx.z * 16;
    int r0  = (tid >> 4) * 8;
    int c0t = (tid & 15) * 8;

    float acc[8][8];
    #pragma unroll
    for (int i = 0; i < 8; ++i)
        #pragma unroll
        for (int j = 0; j < 8; ++j) acc[i][j] = 0.0f;

    for (int k0 = 0; k0 < 96; k0 += 32) {
        for (int idx = tid; idx < 32*128; idx += 256) {
            int ml = idx & 127, kk = idx >> 7;
            int m = m0 + ml;
            int b = m >> 4, tl = m & 15;
            int g = b * T_ + t0 + tl;
            int k = k0 + kk;
            float v = (k < 64) ? sig[g*SIG_ + k] : met[g*MET_ + (k - 64)];
            A_s[kk][ml] = v;
        }
        for (int idx = tid; idx < 32*128; idx += 256) {
            int c = idx & 127, kk = idx >> 7;
            int n = c0b + c;
            W_s[kk][c] = (n < NCOL) ? Wcat[(k0+kk)*NCOL + n] : 0.0f;
        }
        __syncthreads();
        #pragma unroll
        for (int kk = 0; kk < 32; ++kk) {
            float4 a0 = *(const float4*)&A_s[kk][r0];
            float4 a1 = *(const float4*)&A_s[kk][r0+4];
            float4 w0 = *(const float4*)&W_s[kk][c0t];
            float4 w1 = *(const float4*)&W_s[kk][c0t+4];
            float av[8] = {a0.x,a0.y,a0.z,a0.w,a1.x,a1.y,a1.z,a1.w};
            float wv[8] = {w0.x,w0.y,w0.z,w0.w,w1.x,w1.y,w1.z,w1.w};
            #pragma unroll
            for (int i = 0; i < 8; ++i)
                #pragma unroll
                for (int j = 0; j < 8; ++j)
                    acc[i][j] = fmaf(av[i], wv[j], acc[i][j]);
        }
        __syncthreads();
    }
    #pragma unroll
    for (int i = 0; i < 8; ++i) {
        int m = m0 + r0 + i;
        int bb = m >> 4, tl = m & 15;
        size_t row = (size_t)bb * T_ + t0 + tl;
        #pragma unroll
        for (int j = 0; j < 8; ++j) {
            int n = c0b + c0t + j;
            if (n < NCOL) X[row*NCOL + n] = acc[i][j] + bcat[n];
        }
    }
}

// ---------------------------------------------------------------------------
// Phase 2: full recurrence, SINGLE launch. One block (1024 thr, 16 waves) per
// batch element; 128 steps internal; h in LDS, S in registers of the update
// owner (j = tid>>2, f-quarter = tid&3). Dot phase: thread tid owns column
// tid of the 1024 main columns; the 16 fre columns are computed as 64
// quarter-dots on lanes {15,31,47,63} of each wave (wave w -> fre col w).
// ---------------------------------------------------------------------------
__device__ __forceinline__ float dot8(uint4 u, float4 ha, float4 hb, float acc) {
    acc = fmaf(__uint_as_float(u.x << 16),          ha.x, acc);
    acc = fmaf(__uint_as_float(u.x & 0xffff0000u),  ha.y, acc);
    acc = fmaf(__uint_as_float(u.y << 16),          ha.z, acc);
    acc = fmaf(__uint_as_float(u.y & 0xffff0000u),  ha.w, acc);
    acc = fmaf(__uint_as_float(u.z << 16),          hb.x, acc);
    acc = fmaf(__uint_as_float(u.z & 0xffff0000u),  hb.y, acc);
    acc = fmaf(__uint_as_float(u.w << 16),          hb.z, acc);
    acc = fmaf(__uint_as_float(u.w & 0xffff0000u),  hb.w, acc);
    return acc;
}

__global__ __launch_bounds__(1024) void recur_kernel(
    const float* __restrict__ X, const unsigned short* __restrict__ UT,
    const float* __restrict__ U_a, const float* __restrict__ b_a,
    const float* __restrict__ W_p, const float* __restrict__ b_p,
    const float* __restrict__ fc_w, const float* __restrict__ fc_b,
    float* __restrict__ out)
{
    __shared__ float h_s[H_];
    __shared__ float pre_s[1024];
    __shared__ float qp[64];          // fre quarter partials: qp[f*4+q]
    __shared__ float cs_s[16], sn_s[16];

    int tid  = threadIdx.x;
    int b    = blockIdx.x;
    int lane = tid & 63;
    int wid  = tid >> 6;
    bool isfre = ((lane & 15) == 15);
    int fq_dot = lane >> 4;           // quarter 0..3 (when isfre)

    // update-phase ownership: j = tid>>2 (h index), f0 = (tid&3)*4 (f range)
    int j  = tid >> 2;
    int f0 = (tid & 3) * 4;

    if (tid < H_) h_s[tid] = 0.0f;
    if (tid < 16) {
        float ang = (float)tid * 0.39269908169872414f; // 2*pi/16
        cs_s[tid] = cosf(ang);
        sn_s[tid] = sinf(ang);
    }
    float Sre[4], Sim[4];
    #pragma unroll
    for (int r = 0; r < 4; ++r) { Sre[r] = 0.0f; Sim[r] = 0.0f; }

    float ba_j = b_a[j];
    float4 ua4 = ((const float4*)U_a)[tid & 3];
    const uint4* Ucol = (const uint4*)(UT + (size_t)tid * H_);
    const uint4* Ufre = (const uint4*)(UT + (size_t)(1024 + wid) * H_ + fq_dot * 64);
    const float* Xb = X + (size_t)b * T_ * NCOL;

    float hnew = 0.0f;
    __syncthreads();

    for (int t = 0; t < T_; ++t) {
        const float* xrow = Xb + (size_t)t * NCOL;

        // ---- dot phase: pre[col=tid] = x + U[:,col] . h ----
        float acc = xrow[tid];
        #pragma unroll
        for (int k8 = 0; k8 < 32; ++k8) {
            float4 ha = *(const float4*)&h_s[k8*8];
            float4 hb = *(const float4*)&h_s[k8*8 + 4];
            acc = dot8(Ucol[k8], ha, hb, acc);
        }
        float fa = 0.0f;
        if (isfre) {
            #pragma unroll
            for (int q = 0; q < 8; ++q) {
                float4 ha = *(const float4*)&h_s[fq_dot*64 + q*8];
                float4 hb = *(const float4*)&h_s[fq_dot*64 + q*8 + 4];
                fa = dot8(Ufre[q], ha, hb, fa);
            }
        }
        pre_s[tid] = acc;
        if (isfre) qp[wid*4 + fq_dot] = fa;
        __syncthreads();   // A: pre_s + qp ready; h_s reads done

        // ---- update phase ----
        float xi   = pre_s[j];
        float xste = pre_s[256 + j];
        float xc   = pre_s[512 + j];
        float xo   = pre_s[768 + j];
        float gi   = hsig(xi);
        float gste = hsig(xste);
        float go   = hsig(xo);
        float cc   = gi * tanhf(xc);

        float4 xfre = *(const float4*)&xrow[1024 + f0];
        float4 q0 = *(const float4*)&qp[(f0+0)*4];
        float4 q1 = *(const float4*)&qp[(f0+1)*4];
        float4 q2 = *(const float4*)&qp[(f0+2)*4];
        float4 q3 = *(const float4*)&qp[(f0+3)*4];
        float fre[4];
        fre[0] = hsig(xfre.x + q0.x + q0.y + q0.z + q0.w);
        fre[1] = hsig(xfre.y + q1.x + q1.y + q1.z + q1.w);
        fre[2] = hsig(xfre.z + q2.x + q2.y + q2.z + q2.w);
        fre[3] = hsig(xfre.w + q3.x + q3.y + q3.z + q3.w);

        int tt1 = (t + 1) & 15;
        float Aa = 0.0f;
        #pragma unroll
        for (int r = 0; r < 4; ++r) {
            int idx = (tt1 * (f0 + r)) & 15;
            float dec = gste * fre[r];
            float sre = fmaf(dec, Sre[r], cc * cs_s[idx]);
            float sim = fmaf(dec, Sim[r], cc * sn_s[idx]);
            Sre[r] = sre; Sim[r] = sim;
            Aa = fmaf(fmaf(sre, sre, sim*sim), ((const float*)&ua4)[r], Aa);
        }
        Aa += __shfl_xor(Aa, 1);
        Aa += __shfl_xor(Aa, 2);
        if ((tid & 3) == 0) {
            float a = tanhf(Aa + ba_j);
            hnew = go * a;
            h_s[j] = hnew;
        }
        __syncthreads();   // C: h_s ready for next step; pre_s/qp reads done
    }

    // ---- head: out[b] = (sum_j h[j]*W_p[j] + b_p)*fc_w + fc_b ----
    if ((tid & 3) == 0) pre_s[j] = hnew * W_p[j];
    __syncthreads();
    for (int s = 128; s > 0; s >>= 1) {
        if (tid < s) pre_s[tid] += pre_s[tid + s];
        __syncthreads();
    }
    if (tid == 0) out[b] = (pre_s[0] + b_p[0]) * fc_w[0] + fc_b[0];
}

// ---------------------------------------------------------------------------
extern "C" void kernel_launch(void* const* d_in, const int* in_sizes, int n_in,
                              void* d_out, int out_size, void* d_ws, size_t ws_size,
                              hipStream_t stream) {
    const float* signal = (const float*)d_in[0];
    const float* metmast = (const float*)d_in[1];
    const float* W_i_s   = (const float*)d_in[2];
    const float* W_ste_s = (const float*)d_in[3];
    const float* W_fre_s = (const float*)d_in[4];
    const float* W_c_s   = (const float*)d_in[5];
    const float* W_o_s   = (const float*)d_in[6];
    const float* W_i_m   = (const float*)d_in[7];
    const float* W_ste_m = (const float*)d_in[8];
    const float* W_fre_m = (const float*)d_in[9];
    const float* W_c_m   = (const float*)d_in[10];
    const float* W_o_m   = (const float*)d_in[11];
    const float* U_i   = (const float*)d_in[12];
    const float* b_i   = (const float*)d_in[13];
    const float* U_ste = (const float*)d_in[14];
    const float* b_ste = (const float*)d_in[15];
    const float* U_fre = (const float*)d_in[16];
    const float* b_fre = (const float*)d_in[17];
    const float* U_c   = (const float*)d_in[18];
    const float* b_c   = (const float*)d_in[19];
    const float* U_o   = (const float*)d_in[20];
    const float* b_o   = (const float*)d_in[21];
    const float* U_a   = (const float*)d_in[22];
    const float* b_a   = (const float*)d_in[23];
    const float* W_p   = (const float*)d_in[24];
    const float* b_p   = (const float*)d_in[25];
    const float* fc_w  = (const float*)d_in[26];
    const float* fc_b  = (const float*)d_in[27];
    float* out = (float*)d_out;

    char* ws = (char*)d_ws;
    float*          Wcat = (float*)(ws + 0);                 //  96*1040*4 = 399360
    float*          bcat = (float*)(ws + 399360);            //  1040*4    = 4160
    unsigned short* UT   = (unsigned short*)(ws + 403520);   //  1040*256*2 = 532480
    float*          X    = (float*)(ws + 936000);            //  256*128*1040*4 = 136314880
    // total ~137.3 MB

    pack_kernel<<<256, 256, 0, stream>>>(
        W_i_s, W_ste_s, W_fre_s, W_c_s, W_o_s,
        W_i_m, W_ste_m, W_fre_m, W_c_m, W_o_m,
        U_i, U_ste, U_fre, U_c, U_o,
        b_i, b_ste, b_fre, b_c, b_o,
        Wcat, bcat, UT);

    proj_kernel<<<dim3(9, 32, 8), 256, 0, stream>>>(signal, metmast, Wcat, bcat, X);

    recur_kernel<<<B_, 1024, 0, stream>>>(X, UT, U_a, b_a, W_p, b_p, fc_w, fc_b, out);
}

// Round 3
// 8591.888 us; speedup vs baseline: 1.0593x; 1.0593x over previous
//
#include <hip/hip_runtime.h>
#include <cstdint>
#include <cstddef>

#define B_    256
#define T_    128
#define SIG_  64
#define MET_  32
#define H_    256
#define F_    16
#define NCOL  1040   // [i:0..255 | ste:256..511 | c:512..767 | o:768..1023 | fre:1024..1039]

__device__ __forceinline__ float hsig(float x) {
    return fminf(fmaxf(x * (1.0f/6.0f) + 0.5f, 0.0f), 1.0f);
}

__device__ __forceinline__ unsigned short f2bf(float f) {
    unsigned int u = __float_as_uint(f);
    unsigned int r = (u + 0x7fffu + ((u >> 16) & 1u)) >> 16;
    return (unsigned short)r;
}

__device__ __forceinline__ float ntload_f(const float* p) {
    return __builtin_nontemporal_load(p);
}
__device__ __forceinline__ float4 ntload_f4(const float* p) {
    float4 v;
    v.x = __builtin_nontemporal_load(p + 0);
    v.y = __builtin_nontemporal_load(p + 1);
    v.z = __builtin_nontemporal_load(p + 2);
    v.w = __builtin_nontemporal_load(p + 3);
    return v;
}

// column order: i(256) | ste(256) | c(256) | o(256) | fre(16)
__device__ __forceinline__ void colmap(int n, int& sec, int& idx) {
    if (n < 256)       { sec = 0; idx = n; }
    else if (n < 512)  { sec = 1; idx = n - 256; }
    else if (n < 768)  { sec = 2; idx = n - 512; }
    else if (n < 1024) { sec = 3; idx = n - 768; }
    else               { sec = 4; idx = n - 1024; }
}

// ---------------------------------------------------------------------------
// Pack weights: Wcat[96][1040] f32, bcat[1040] f32, UT[1040][256] bf16 (U^T)
// ---------------------------------------------------------------------------
__global__ __launch_bounds__(256) void pack_kernel(
    const float* __restrict__ Wis, const float* __restrict__ Wstes, const float* __restrict__ Wfres,
    const float* __restrict__ Wcs, const float* __restrict__ Wos,
    const float* __restrict__ Wim, const float* __restrict__ Wstem, const float* __restrict__ Wfrem,
    const float* __restrict__ Wcm, const float* __restrict__ Wom,
    const float* __restrict__ Ui, const float* __restrict__ Uste, const float* __restrict__ Ufre,
    const float* __restrict__ Uc, const float* __restrict__ Uo,
    const float* __restrict__ bi, const float* __restrict__ bste, const float* __restrict__ bfre,
    const float* __restrict__ bc, const float* __restrict__ bo,
    float* __restrict__ Wcat, float* __restrict__ bcat, unsigned short* __restrict__ UT)
{
    int gtid = blockIdx.x * blockDim.x + threadIdx.x;
    int stride = gridDim.x * blockDim.x;
    const float* Wsig[5] = {Wis, Wstes, Wcs, Wos, Wfres};
    const float* Wmet[5] = {Wim, Wstem, Wcm, Wom, Wfrem};
    const float* Us[5]   = {Ui, Uste, Uc, Uo, Ufre};
    const float* bs[5]   = {bi, bste, bc, bo, bfre};

    for (int i = gtid; i < 96*NCOL; i += stride) {
        int k = i / NCOL, n = i - k*NCOL;
        int sec, idx; colmap(n, sec, idx);
        int secN = (sec == 4) ? F_ : H_;
        float v = (k < 64) ? Wsig[sec][k*secN + idx] : Wmet[sec][(k-64)*secN + idx];
        Wcat[k*NCOL + n] = v;
    }
    for (int n = gtid; n < NCOL; n += stride) {
        int sec, idx; colmap(n, sec, idx);
        bcat[n] = bs[sec][idx];
    }
    for (int i = gtid; i < NCOL*H_; i += stride) {
        int n = i >> 8, k = i & 255;
        int sec, idx; colmap(n, sec, idx);
        int secN = (sec == 4) ? F_ : H_;
        UT[n*H_ + k] = f2bf(Us[sec][k*secN + idx]);
    }
}

// ---------------------------------------------------------------------------
// Phase 1: input projection GEMM for ALL time steps (z = chunk of 16 steps).
// X stores are NON-TEMPORAL: X is written once, read once — do not let it
// occupy/evict L2 lines (UT must stay L2-resident for the recurrence).
// ---------------------------------------------------------------------------
__global__ __launch_bounds__(256) void proj_kernel(
    const float* __restrict__ sig, const float* __restrict__ met,
    const float* __restrict__ Wcat, const float* __restrict__ bcat,
    float* __restrict__ X)
{
    __shared__ float A_s[32][128];
    __shared__ float W_s[32][128];
    int tid = threadIdx.x;
    int c0b = blockIdx.x * 128;
    int m0  = blockIdx.y * 128;
    int t0  = blockIdx.z * 16;
    int r0  = (tid >> 4) * 8;
    int c0t = (tid & 15) * 8;

    float acc[8][8];
    #pragma unroll
    for (int i = 0; i < 8; ++i)
        #pragma unroll
        for (int j = 0; j < 8; ++j) acc[i][j] = 0.0f;

    for (int k0 = 0; k0 < 96; k0 += 32) {
        for (int idx = tid; idx < 32*128; idx += 256) {
            int ml = idx & 127, kk = idx >> 7;
            int m = m0 + ml;
            int b = m >> 4, tl = m & 15;
            int g = b * T_ + t0 + tl;
            int k = k0 + kk;
            float v = (k < 64) ? ntload_f(&sig[g*SIG_ + k]) : ntload_f(&met[g*MET_ + (k - 64)]);
            A_s[kk][ml] = v;
        }
        for (int idx = tid; idx < 32*128; idx += 256) {
            int c = idx & 127, kk = idx >> 7;
            int n = c0b + c;
            W_s[kk][c] = (n < NCOL) ? Wcat[(k0+kk)*NCOL + n] : 0.0f;
        }
        __syncthreads();
        #pragma unroll
        for (int kk = 0; kk < 32; ++kk) {
            float4 a0 = *(const float4*)&A_s[kk][r0];
            float4 a1 = *(const float4*)&A_s[kk][r0+4];
            float4 w0 = *(const float4*)&W_s[kk][c0t];
            float4 w1 = *(const float4*)&W_s[kk][c0t+4];
            float av[8] = {a0.x,a0.y,a0.z,a0.w,a1.x,a1.y,a1.z,a1.w};
            float wv[8] = {w0.x,w0.y,w0.z,w0.w,w1.x,w1.y,w1.z,w1.w};
            #pragma unroll
            for (int i = 0; i < 8; ++i)
                #pragma unroll
                for (int j = 0; j < 8; ++j)
                    acc[i][j] = fmaf(av[i], wv[j], acc[i][j]);
        }
        __syncthreads();
    }
    #pragma unroll
    for (int i = 0; i < 8; ++i) {
        int m = m0 + r0 + i;
        int bb = m >> 4, tl = m & 15;
        size_t row = (size_t)bb * T_ + t0 + tl;
        #pragma unroll
        for (int j = 0; j < 8; ++j) {
            int n = c0b + c0t + j;
            if (n < NCOL)
                __builtin_nontemporal_store(acc[i][j] + bcat[n], &X[row*NCOL + n]);
        }
    }
}

// ---------------------------------------------------------------------------
// Phase 2: full recurrence, SINGLE launch. One block (1024 thr, 16 waves) per
// batch element. X reads are NON-TEMPORAL (one-touch stream must not evict
// the every-step-hot UT from L2). UT reads stay cached.
// ---------------------------------------------------------------------------
__device__ __forceinline__ float dot8(uint4 u, float4 ha, float4 hb, float acc) {
    acc = fmaf(__uint_as_float(u.x << 16),          ha.x, acc);
    acc = fmaf(__uint_as_float(u.x & 0xffff0000u),  ha.y, acc);
    acc = fmaf(__uint_as_float(u.y << 16),          ha.z, acc);
    acc = fmaf(__uint_as_float(u.y & 0xffff0000u),  ha.w, acc);
    acc = fmaf(__uint_as_float(u.z << 16),          hb.x, acc);
    acc = fmaf(__uint_as_float(u.z & 0xffff0000u),  hb.y, acc);
    acc = fmaf(__uint_as_float(u.w << 16),          hb.z, acc);
    acc = fmaf(__uint_as_float(u.w & 0xffff0000u),  hb.w, acc);
    return acc;
}

__global__ __launch_bounds__(1024) void recur_kernel(
    const float* __restrict__ X, const unsigned short* __restrict__ UT,
    const float* __restrict__ U_a, const float* __restrict__ b_a,
    const float* __restrict__ W_p, const float* __restrict__ b_p,
    const float* __restrict__ fc_w, const float* __restrict__ fc_b,
    float* __restrict__ out)
{
    __shared__ float h_s[H_];
    __shared__ float pre_s[1024];
    __shared__ float qp[64];          // fre quarter partials: qp[f*4+q]
    __shared__ float cs_s[16], sn_s[16];

    int tid  = threadIdx.x;
    int b    = blockIdx.x;
    int lane = tid & 63;
    int wid  = tid >> 6;
    bool isfre = ((lane & 15) == 15);
    int fq_dot = lane >> 4;           // quarter 0..3 (when isfre)

    // update-phase ownership: j = tid>>2 (h index), f0 = (tid&3)*4 (f range)
    int j  = tid >> 2;
    int f0 = (tid & 3) * 4;

    if (tid < H_) h_s[tid] = 0.0f;
    if (tid < 16) {
        float ang = (float)tid * 0.39269908169872414f; // 2*pi/16
        cs_s[tid] = cosf(ang);
        sn_s[tid] = sinf(ang);
    }
    float Sre[4], Sim[4];
    #pragma unroll
    for (int r = 0; r < 4; ++r) { Sre[r] = 0.0f; Sim[r] = 0.0f; }

    float ba_j = b_a[j];
    float4 ua4 = ((const float4*)U_a)[tid & 3];
    const uint4* Ucol = (const uint4*)(UT + (size_t)tid * H_);
    const uint4* Ufre = (const uint4*)(UT + (size_t)(1024 + wid) * H_ + fq_dot * 64);
    const float* Xb = X + (size_t)b * T_ * NCOL;

    float hnew = 0.0f;
    __syncthreads();

    for (int t = 0; t < T_; ++t) {
        const float* xrow = Xb + (size_t)t * NCOL;

        // ---- dot phase: pre[col=tid] = x + U[:,col] . h ----
        float acc = ntload_f(&xrow[tid]);
        #pragma unroll
        for (int k8 = 0; k8 < 32; ++k8) {
            float4 ha = *(const float4*)&h_s[k8*8];
            float4 hb = *(const float4*)&h_s[k8*8 + 4];
            acc = dot8(Ucol[k8], ha, hb, acc);
        }
        float fa = 0.0f;
        if (isfre) {
            #pragma unroll
            for (int q = 0; q < 8; ++q) {
                float4 ha = *(const float4*)&h_s[fq_dot*64 + q*8];
                float4 hb = *(const float4*)&h_s[fq_dot*64 + q*8 + 4];
                fa = dot8(Ufre[q], ha, hb, fa);
            }
        }
        pre_s[tid] = acc;
        if (isfre) qp[wid*4 + fq_dot] = fa;
        __syncthreads();   // A: pre_s + qp ready; h_s reads done

        // ---- update phase ----
        float xi   = pre_s[j];
        float xste = pre_s[256 + j];
        float xc   = pre_s[512 + j];
        float xo   = pre_s[768 + j];
        float gi   = hsig(xi);
        float gste = hsig(xste);
        float go   = hsig(xo);
        float cc   = gi * tanhf(xc);

        float4 xfre = ntload_f4(&xrow[1024 + f0]);
        float4 q0 = *(const float4*)&qp[(f0+0)*4];
        float4 q1 = *(const float4*)&qp[(f0+1)*4];
        float4 q2 = *(const float4*)&qp[(f0+2)*4];
        float4 q3 = *(const float4*)&qp[(f0+3)*4];
        float fre[4];
        fre[0] = hsig(xfre.x + q0.x + q0.y + q0.z + q0.w);
        fre[1] = hsig(xfre.y + q1.x + q1.y + q1.z + q1.w);
        fre[2] = hsig(xfre.z + q2.x + q2.y + q2.z + q2.w);
        fre[3] = hsig(xfre.w + q3.x + q3.y + q3.z + q3.w);

        int tt1 = (t + 1) & 15;
        float Aa = 0.0f;
        #pragma unroll
        for (int r = 0; r < 4; ++r) {
            int idx = (tt1 * (f0 + r)) & 15;
            float dec = gste * fre[r];
            float sre = fmaf(dec, Sre[r], cc * cs_s[idx]);
            float sim = fmaf(dec, Sim[r], cc * sn_s[idx]);
            Sre[r] = sre; Sim[r] = sim;
            Aa = fmaf(fmaf(sre, sre, sim*sim), ((const float*)&ua4)[r], Aa);
        }
        Aa += __shfl_xor(Aa, 1);
        Aa += __shfl_xor(Aa, 2);
        if ((tid & 3) == 0) {
            float a = tanhf(Aa + ba_j);
            hnew = go * a;
            h_s[j] = hnew;
        }
        __syncthreads();   // C: h_s ready for next step; pre_s/qp reads done
    }

    // ---- head: out[b] = (sum_j h[j]*W_p[j] + b_p)*fc_w + fc_b ----
    if ((tid & 3) == 0) pre_s[j] = hnew * W_p[j];
    __syncthreads();
    for (int s = 128; s > 0; s >>= 1) {
        if (tid < s) pre_s[tid] += pre_s[tid + s];
        __syncthreads();
    }
    if (tid == 0) out[b] = (pre_s[0] + b_p[0]) * fc_w[0] + fc_b[0];
}

// ---------------------------------------------------------------------------
extern "C" void kernel_launch(void* const* d_in, const int* in_sizes, int n_in,
                              void* d_out, int out_size, void* d_ws, size_t ws_size,
                              hipStream_t stream) {
    const float* signal = (const float*)d_in[0];
    const float* metmast = (const float*)d_in[1];
    const float* W_i_s   = (const float*)d_in[2];
    const float* W_ste_s = (const float*)d_in[3];
    const float* W_fre_s = (const float*)d_in[4];
    const float* W_c_s   = (const float*)d_in[5];
    const float* W_o_s   = (const float*)d_in[6];
    const float* W_i_m   = (const float*)d_in[7];
    const float* W_ste_m = (const float*)d_in[8];
    const float* W_fre_m = (const float*)d_in[9];
    const float* W_c_m   = (const float*)d_in[10];
    const float* W_o_m   = (const float*)d_in[11];
    const float* U_i   = (const float*)d_in[12];
    const float* b_i   = (const float*)d_in[13];
    const float* U_ste = (const float*)d_in[14];
    const float* b_ste = (const float*)d_in[15];
    const float* U_fre = (const float*)d_in[16];
    const float* b_fre = (const float*)d_in[17];
    const float* U_c   = (const float*)d_in[18];
    const float* b_c   = (const float*)d_in[19];
    const float* U_o   = (const float*)d_in[20];
    const float* b_o   = (const float*)d_in[21];
    const float* U_a   = (const float*)d_in[22];
    const float* b_a   = (const float*)d_in[23];
    const float* W_p   = (const float*)d_in[24];
    const float* b_p   = (const float*)d_in[25];
    const float* fc_w  = (const float*)d_in[26];
    const float* fc_b  = (const float*)d_in[27];
    float* out = (float*)d_out;

    char* ws = (char*)d_ws;
    float*          Wcat = (float*)(ws + 0);                 //  96*1040*4 = 399360
    float*          bcat = (float*)(ws + 399360);            //  1040*4    = 4160
    unsigned short* UT   = (unsigned short*)(ws + 403520);   //  1040*256*2 = 532480
    float*          X    = (float*)(ws + 936000);            //  256*128*1040*4 = 136314880
    // total ~137.3 MB

    pack_kernel<<<256, 256, 0, stream>>>(
        W_i_s, W_ste_s, W_fre_s, W_c_s, W_o_s,
        W_i_m, W_ste_m, W_fre_m, W_c_m, W_o_m,
        U_i, U_ste, U_fre, U_c, U_o,
        b_i, b_ste, b_fre, b_c, b_o,
        Wcat, bcat, UT);

    proj_kernel<<<dim3(9, 32, 8), 256, 0, stream>>>(signal, metmast, Wcat, bcat, X);

    recur_kernel<<<B_, 1024, 0, stream>>>(X, UT, U_a, b_a, W_p, b_p, fc_w, fc_b, out);
}